// Round 3
// baseline (181.095 us; speedup 1.0000x reference)
//
#include <hip/hip_runtime.h>
#include <math.h>

#define C_CLS   19
#define H_IN    97
#define W_IN    97
#define HW_IN   (H_IN * W_IN)
#define CHW_IN  (C_CLS * HW_IN)
#define H_OUT   769
#define W_OUT   769
#define N_BATCH 4
#define NPIX    (N_BATCH * H_OUT * W_OUT)
#define IGNORE_LBL 255
#define MIN_KEPT   100000
#define NHI     110          // histogram bins for p in (0.7, 1.0]
#define ACC_STRIDE 1024      // floats per pred accumulator block in ws
#define NLL_THR 0.35667494f  // -ln(0.7); p <= 0.7  <=>  nll >= NLL_THR
#define ROWP    100          // padded LDS row length (>= 98)

// Cityscapes class weights
__device__ const float c_class_w[C_CLS] = {
    0.8373f, 0.918f,  0.866f,  1.0345f, 1.0166f, 0.9969f, 0.9754f,
    1.0489f, 0.8786f, 1.0023f, 0.9539f, 0.9843f, 1.1116f, 0.9037f,
    1.0865f, 1.0955f, 1.0865f, 1.1529f, 1.0507f};

// ws float layout per pred (pr*ACC_STRIDE):
// [0] sum_w (p<=0.7,valid)  [1] sum_w*nll  [2] count(p<=0.7)  [3] count(valid)
// [4..113] hi_cnt  [114..223] hi_sum_w  [224..333] hi_sum_wnll

__device__ __forceinline__ float max19(const float v[C_CLS]) {
    float p0 = fmaxf(v[0], v[1]);
    float p1 = fmaxf(v[2], v[3]);
    float p2 = fmaxf(v[4], v[5]);
    float p3 = fmaxf(v[6], v[7]);
    float p4 = fmaxf(v[8], v[9]);
    float p5 = fmaxf(v[10], v[11]);
    float p6 = fmaxf(v[12], v[13]);
    float p7 = fmaxf(v[14], v[15]);
    float p8 = fmaxf(v[16], v[17]);
    p0 = fmaxf(p0, p1); p2 = fmaxf(p2, p3);
    p4 = fmaxf(p4, p5); p6 = fmaxf(p6, p7);
    p8 = fmaxf(p8, v[18]);
    p0 = fmaxf(p0, p2); p4 = fmaxf(p4, p6);
    return fmaxf(fmaxf(p0, p4), p8);
}

__device__ __forceinline__ float expsum19(const float v[C_CLS], float m) {
    float s0 = 0.0f, s1 = 0.0f, s2 = 0.0f, s3 = 0.0f;
    #pragma unroll
    for (int c = 0; c < 16; c += 4) {
        s0 += __expf(v[c + 0] - m);
        s1 += __expf(v[c + 1] - m);
        s2 += __expf(v[c + 2] - m);
        s3 += __expf(v[c + 3] - m);
    }
    s0 += __expf(v[16] - m);
    s1 += __expf(v[17] - m);
    s2 += __expf(v[18] - m);
    return (s0 + s1) + (s2 + s3);
}

__global__ __launch_bounds__(256) void ohem_row(
    const float* __restrict__ pred1, const float* __restrict__ pred2,
    const int* __restrict__ target, float* __restrict__ ws)
{
    const int row = blockIdx.x;           // 0 .. 4*769-1
    const int n   = row / H_OUT;
    const int y   = row - n * H_OUT;
    const int tid = threadIdx.x;

    __shared__ float ry[2][C_CLS][ROWP];  // y-interpolated source rows
    __shared__ float sh_hi[2][3][NHI];    // rare p>0.7 histogram
    __shared__ float sh_red[4][8];

    for (int i = tid; i < 2 * 3 * NHI; i += 256)
        (&sh_hi[0][0][0])[i] = 0.0f;

    const float scl = (float)H_IN / (float)H_OUT;

    // ---- uniform y-interp params for this output row ----
    float sy = fmaxf(fmaf((float)y + 0.5f, scl, -0.5f), 0.0f);
    int   y0 = min((int)sy, H_IN - 1);
    float fy = sy - (float)y0;
    int   y1 = min(y0 + 1, H_IN - 1);

    // ---- stage y-interpolated rows into LDS (coalesced, independent) ----
    const float* __restrict__ b1 = pred1 + (size_t)n * CHW_IN;
    const float* __restrict__ b2 = pred2 + (size_t)n * CHW_IN;
    for (int j = tid; j < C_CLS * W_IN; j += 256) {
        int c = j / W_IN;
        int x = j - c * W_IN;
        int o0 = c * HW_IN + y0 * W_IN + x;
        int o1 = c * HW_IN + y1 * W_IN + x;
        float a0 = b1[o0], a1 = b1[o1];
        float c0 = b2[o0], c1 = b2[o1];
        float r1 = fmaf(fy, a1 - a0, a0);
        float r2 = fmaf(fy, c1 - c0, c0);
        ry[0][c][x] = r1;
        ry[1][c][x] = r2;
        if (x == W_IN - 1) {              // pad so x0+1 read is safe & exact
            ry[0][c][W_IN] = r1;
            ry[1][c][W_IN] = r2;
        }
    }
    __syncthreads();

    // ---- per-pixel pass over this output row ----
    float a_nv = 0.0f;
    float a_w1 = 0.0f, a_wlp1 = 0.0f, a_cle1 = 0.0f;
    float a_w2 = 0.0f, a_wlp2 = 0.0f, a_cle2 = 0.0f;
    const int rowbase = (n * H_OUT + y) * W_OUT;

    #pragma unroll
    for (int i = 0; i < 4; ++i) {
        int x = tid + i * 256;
        if (x < W_OUT) {
            int t = target[rowbase + x];
            bool valid = (t != IGNORE_LBL);
            int ts = valid ? t : 0;

            float sx = fmaxf(fmaf((float)x + 0.5f, scl, -0.5f), 0.0f);
            int   x0 = min((int)sx, W_IN - 1);
            float fx = sx - (float)x0;

            float v1[C_CLS], v2[C_CLS];
            #pragma unroll
            for (int c = 0; c < C_CLS; ++c) {
                float a0 = ry[0][c][x0];
                float a1 = ry[0][c][x0 + 1];
                v1[c] = fmaf(fx, a1 - a0, a0);
                float q0 = ry[1][c][x0];
                float q1 = ry[1][c][x0 + 1];
                v2[c] = fmaf(fx, q1 - q0, q0);
            }
            float lt1 = v1[0], lt2 = v2[0];
            #pragma unroll
            for (int c = 1; c < C_CLS; ++c) {
                lt1 = (ts == c) ? v1[c] : lt1;
                lt2 = (ts == c) ? v2[c] : lt2;
            }

            float m1 = max19(v1);
            float m2 = max19(v2);
            float s1 = expsum19(v1, m1);
            float s2 = expsum19(v2, m2);

            if (valid) {
                a_nv += 1.0f;
                float w = c_class_w[ts];
                float nll1 = __logf(s1) - (lt1 - m1);
                float nll2 = __logf(s2) - (lt2 - m2);

                if (nll1 >= NLL_THR) {
                    a_w1 += w; a_wlp1 += w * nll1; a_cle1 += 1.0f;
                } else {
                    float p = __expf(-nll1);
                    int b = min(max((int)((p - 0.7f) * (109.0f / 0.3f)), 0), NHI - 1);
                    atomicAdd(&sh_hi[0][0][b], 1.0f);
                    atomicAdd(&sh_hi[0][1][b], w);
                    atomicAdd(&sh_hi[0][2][b], w * nll1);
                }
                if (nll2 >= NLL_THR) {
                    a_w2 += w; a_wlp2 += w * nll2; a_cle2 += 1.0f;
                } else {
                    float p = __expf(-nll2);
                    int b = min(max((int)((p - 0.7f) * (109.0f / 0.3f)), 0), NHI - 1);
                    atomicAdd(&sh_hi[1][0][b], 1.0f);
                    atomicAdd(&sh_hi[1][1][b], w);
                    atomicAdd(&sh_hi[1][2][b], w * nll2);
                }
            }
        }
    }

    // ---- wave butterfly reduce, 7 values ----
    #pragma unroll
    for (int off = 32; off > 0; off >>= 1) {
        a_nv   += __shfl_down(a_nv, off);
        a_w1   += __shfl_down(a_w1, off);
        a_wlp1 += __shfl_down(a_wlp1, off);
        a_cle1 += __shfl_down(a_cle1, off);
        a_w2   += __shfl_down(a_w2, off);
        a_wlp2 += __shfl_down(a_wlp2, off);
        a_cle2 += __shfl_down(a_cle2, off);
    }
    int lane = tid & 63;
    int wv   = tid >> 6;
    if (lane == 0) {
        sh_red[wv][0] = a_nv;
        sh_red[wv][1] = a_w1; sh_red[wv][2] = a_wlp1; sh_red[wv][3] = a_cle1;
        sh_red[wv][4] = a_w2; sh_red[wv][5] = a_wlp2; sh_red[wv][6] = a_cle2;
    }
    __syncthreads();
    if (tid == 0) {
        float r[7] = {0, 0, 0, 0, 0, 0, 0};
        #pragma unroll
        for (int i = 0; i < 4; ++i)
            #pragma unroll
            for (int j = 0; j < 7; ++j) r[j] += sh_red[i][j];
        atomicAdd(&ws[0], r[1]); atomicAdd(&ws[1], r[2]);
        atomicAdd(&ws[2], r[3]); atomicAdd(&ws[3], r[0]);
        atomicAdd(&ws[ACC_STRIDE + 0], r[4]); atomicAdd(&ws[ACC_STRIDE + 1], r[5]);
        atomicAdd(&ws[ACC_STRIDE + 2], r[6]); atomicAdd(&ws[ACC_STRIDE + 3], r[0]);
    }
    for (int i = tid; i < NHI; i += 256) {
        if (sh_hi[0][0][i] != 0.0f) {
            atomicAdd(&ws[4 + i],   sh_hi[0][0][i]);
            atomicAdd(&ws[114 + i], sh_hi[0][1][i]);
            atomicAdd(&ws[224 + i], sh_hi[0][2][i]);
        }
        if (sh_hi[1][0][i] != 0.0f) {
            atomicAdd(&ws[ACC_STRIDE + 4 + i],   sh_hi[1][0][i]);
            atomicAdd(&ws[ACC_STRIDE + 114 + i], sh_hi[1][1][i]);
            atomicAdd(&ws[ACC_STRIDE + 224 + i], sh_hi[1][2][i]);
        }
    }
}

__global__ void ohem_finalize(const float* __restrict__ ws, float* __restrict__ out)
{
    if (threadIdx.x != 0 || blockIdx.x != 0) return;
    float loss[2];
    for (int pr = 0; pr < 2; ++pr) {
        const float* a = ws + pr * ACC_STRIDE;
        float sw = a[0], swlp = a[1], cle = a[2], nv = a[3];
        float l;
        if (nv <= (float)MIN_KEPT) {
            float tw = sw, twlp = swlp;
            for (int b = 0; b < NHI; ++b) { tw += a[114 + b]; twlp += a[224 + b]; }
            l = twlp / tw;
        } else if (cle >= (float)MIN_KEPT) {
            l = swlp / sw;
        } else {
            float cum = cle, tw = sw, twlp = swlp;
            for (int b = 0; b < NHI; ++b) {
                cum  += a[4 + b];
                tw   += a[114 + b];
                twlp += a[224 + b];
                if (cum >= (float)MIN_KEPT) break;
            }
            l = twlp / tw;
        }
        loss[pr] = l;
    }
    out[0] = 0.4f * loss[0] + loss[1];
}

extern "C" void kernel_launch(void* const* d_in, const int* in_sizes, int n_in,
                              void* d_out, int out_size, void* d_ws, size_t ws_size,
                              hipStream_t stream)
{
    const float* pred1  = (const float*)d_in[0];
    const float* pred2  = (const float*)d_in[1];
    const int*   target = (const int*)d_in[2];
    float* out = (float*)d_out;
    float* ws  = (float*)d_ws;

    hipMemsetAsync(d_ws, 0, 2 * ACC_STRIDE * sizeof(float), stream);

    ohem_row<<<dim3(N_BATCH * H_OUT), 256, 0, stream>>>(pred1, pred2, target, ws);
    ohem_finalize<<<1, 64, 0, stream>>>(ws, out);
}

// Round 4
// 48.211 us; speedup vs baseline: 3.7563x; 3.7563x over previous
//
#include <hip/hip_runtime.h>
#include <math.h>

#define C_CLS   19
#define H_IN    97
#define W_IN    97
#define HW_IN   (H_IN * W_IN)
#define CHW_IN  (C_CLS * HW_IN)
#define H_OUT   769
#define W_OUT   769
#define N_BATCH 4
#define NPIX    (N_BATCH * H_OUT * W_OUT)
#define IGNORE_LBL 255
#define MIN_KEPT   100000
#define NHI     110          // histogram bins for p in (0.7, 1.0]
#define ACC_STRIDE 1024      // floats per pred histogram block in ws
#define NSETS   64           // striped accumulator sets (1 cache line each)
#define SET_BASE 2048        // ws float offset of striped sets
#define NLL_THR 0.35667494f  // -ln(0.7); p <= 0.7  <=>  nll >= NLL_THR
#define ROWP    100          // padded LDS row length (>= 98)

// Cityscapes class weights
__device__ const float c_class_w[C_CLS] = {
    0.8373f, 0.918f,  0.866f,  1.0345f, 1.0166f, 0.9969f, 0.9754f,
    1.0489f, 0.8786f, 1.0023f, 0.9539f, 0.9843f, 1.1116f, 0.9037f,
    1.0865f, 1.0955f, 1.0865f, 1.1529f, 1.0507f};

// ws layout (floats):
// [4..333]            hist pred1: cnt / sum_w / sum_wnll  (stride 110 each)
// [1028..1357]        hist pred2
// [2048 + s*16 + k]   striped accumulator set s (k: 0=nv 1=w1 2=wlp1 3=cle1
//                                                   4=w2 5=wlp2 6=cle2)

__device__ __forceinline__ float max19(const float v[C_CLS]) {
    float p0 = fmaxf(v[0], v[1]);
    float p1 = fmaxf(v[2], v[3]);
    float p2 = fmaxf(v[4], v[5]);
    float p3 = fmaxf(v[6], v[7]);
    float p4 = fmaxf(v[8], v[9]);
    float p5 = fmaxf(v[10], v[11]);
    float p6 = fmaxf(v[12], v[13]);
    float p7 = fmaxf(v[14], v[15]);
    float p8 = fmaxf(v[16], v[17]);
    p0 = fmaxf(p0, p1); p2 = fmaxf(p2, p3);
    p4 = fmaxf(p4, p5); p6 = fmaxf(p6, p7);
    p8 = fmaxf(p8, v[18]);
    p0 = fmaxf(p0, p2); p4 = fmaxf(p4, p6);
    return fmaxf(fmaxf(p0, p4), p8);
}

__device__ __forceinline__ float expsum19(const float v[C_CLS], float m) {
    float s0 = 0.0f, s1 = 0.0f, s2 = 0.0f, s3 = 0.0f;
    #pragma unroll
    for (int c = 0; c < 16; c += 4) {
        s0 += __expf(v[c + 0] - m);
        s1 += __expf(v[c + 1] - m);
        s2 += __expf(v[c + 2] - m);
        s3 += __expf(v[c + 3] - m);
    }
    s0 += __expf(v[16] - m);
    s1 += __expf(v[17] - m);
    s2 += __expf(v[18] - m);
    return (s0 + s1) + (s2 + s3);
}

__global__ __launch_bounds__(256) void ohem_row(
    const float* __restrict__ pred1, const float* __restrict__ pred2,
    const int* __restrict__ target, float* __restrict__ ws)
{
    const int row = blockIdx.x;           // 0 .. 4*769-1
    const int n   = row / H_OUT;
    const int y   = row - n * H_OUT;
    const int tid = threadIdx.x;

    __shared__ float ry[2][C_CLS][ROWP];  // y-interpolated source rows
    __shared__ float sh_hi[2][3][NHI];    // rare p>0.7 histogram
    __shared__ float sh_red[4][8];

    for (int i = tid; i < 2 * 3 * NHI; i += 256)
        (&sh_hi[0][0][0])[i] = 0.0f;

    const float scl = (float)H_IN / (float)H_OUT;

    float sy = fmaxf(fmaf((float)y + 0.5f, scl, -0.5f), 0.0f);
    int   y0 = min((int)sy, H_IN - 1);
    float fy = sy - (float)y0;
    int   y1 = min(y0 + 1, H_IN - 1);

    const float* __restrict__ b1 = pred1 + (size_t)n * CHW_IN;
    const float* __restrict__ b2 = pred2 + (size_t)n * CHW_IN;
    for (int j = tid; j < C_CLS * W_IN; j += 256) {
        int c = j / W_IN;
        int x = j - c * W_IN;
        int o0 = c * HW_IN + y0 * W_IN + x;
        int o1 = c * HW_IN + y1 * W_IN + x;
        float a0 = b1[o0], a1 = b1[o1];
        float c0 = b2[o0], c1 = b2[o1];
        float r1 = fmaf(fy, a1 - a0, a0);
        float r2 = fmaf(fy, c1 - c0, c0);
        ry[0][c][x] = r1;
        ry[1][c][x] = r2;
        if (x == W_IN - 1) {
            ry[0][c][W_IN] = r1;
            ry[1][c][W_IN] = r2;
        }
    }
    __syncthreads();

    float a_nv = 0.0f;
    float a_w1 = 0.0f, a_wlp1 = 0.0f, a_cle1 = 0.0f;
    float a_w2 = 0.0f, a_wlp2 = 0.0f, a_cle2 = 0.0f;
    const int rowbase = (n * H_OUT + y) * W_OUT;

    #pragma unroll
    for (int i = 0; i < 4; ++i) {
        int x = tid + i * 256;
        if (x < W_OUT) {
            int t = target[rowbase + x];
            bool valid = (t != IGNORE_LBL);
            int ts = valid ? t : 0;

            float sx = fmaxf(fmaf((float)x + 0.5f, scl, -0.5f), 0.0f);
            int   x0 = min((int)sx, W_IN - 1);
            float fx = sx - (float)x0;

            float v1[C_CLS], v2[C_CLS];
            #pragma unroll
            for (int c = 0; c < C_CLS; ++c) {
                float a0 = ry[0][c][x0];
                float a1 = ry[0][c][x0 + 1];
                v1[c] = fmaf(fx, a1 - a0, a0);
                float q0 = ry[1][c][x0];
                float q1 = ry[1][c][x0 + 1];
                v2[c] = fmaf(fx, q1 - q0, q0);
            }
            float lt1 = v1[0], lt2 = v2[0];
            #pragma unroll
            for (int c = 1; c < C_CLS; ++c) {
                lt1 = (ts == c) ? v1[c] : lt1;
                lt2 = (ts == c) ? v2[c] : lt2;
            }

            float m1 = max19(v1);
            float m2 = max19(v2);
            float s1 = expsum19(v1, m1);
            float s2 = expsum19(v2, m2);

            if (valid) {
                a_nv += 1.0f;
                float w = c_class_w[ts];
                float nll1 = __logf(s1) - (lt1 - m1);
                float nll2 = __logf(s2) - (lt2 - m2);

                if (nll1 >= NLL_THR) {
                    a_w1 += w; a_wlp1 += w * nll1; a_cle1 += 1.0f;
                } else {
                    float p = __expf(-nll1);
                    int b = min(max((int)((p - 0.7f) * (109.0f / 0.3f)), 0), NHI - 1);
                    atomicAdd(&sh_hi[0][0][b], 1.0f);
                    atomicAdd(&sh_hi[0][1][b], w);
                    atomicAdd(&sh_hi[0][2][b], w * nll1);
                }
                if (nll2 >= NLL_THR) {
                    a_w2 += w; a_wlp2 += w * nll2; a_cle2 += 1.0f;
                } else {
                    float p = __expf(-nll2);
                    int b = min(max((int)((p - 0.7f) * (109.0f / 0.3f)), 0), NHI - 1);
                    atomicAdd(&sh_hi[1][0][b], 1.0f);
                    atomicAdd(&sh_hi[1][1][b], w);
                    atomicAdd(&sh_hi[1][2][b], w * nll2);
                }
            }
        }
    }

    #pragma unroll
    for (int off = 32; off > 0; off >>= 1) {
        a_nv   += __shfl_down(a_nv, off);
        a_w1   += __shfl_down(a_w1, off);
        a_wlp1 += __shfl_down(a_wlp1, off);
        a_cle1 += __shfl_down(a_cle1, off);
        a_w2   += __shfl_down(a_w2, off);
        a_wlp2 += __shfl_down(a_wlp2, off);
        a_cle2 += __shfl_down(a_cle2, off);
    }
    int lane = tid & 63;
    int wv   = tid >> 6;
    if (lane == 0) {
        sh_red[wv][0] = a_nv;
        sh_red[wv][1] = a_w1; sh_red[wv][2] = a_wlp1; sh_red[wv][3] = a_cle1;
        sh_red[wv][4] = a_w2; sh_red[wv][5] = a_wlp2; sh_red[wv][6] = a_cle2;
    }
    __syncthreads();
    if (tid == 0) {
        float r[7] = {0, 0, 0, 0, 0, 0, 0};
        #pragma unroll
        for (int i = 0; i < 4; ++i)
            #pragma unroll
            for (int j = 0; j < 7; ++j) r[j] += sh_red[i][j];
        // striped accumulator: one 64B line per set -> ~48 blocks/line chain
        float* acc = ws + SET_BASE + (blockIdx.x & (NSETS - 1)) * 16;
        #pragma unroll
        for (int j = 0; j < 7; ++j) atomicAdd(&acc[j], r[j]);
    }
    for (int i = tid; i < NHI; i += 256) {
        if (sh_hi[0][0][i] != 0.0f) {
            atomicAdd(&ws[4 + i],   sh_hi[0][0][i]);
            atomicAdd(&ws[114 + i], sh_hi[0][1][i]);
            atomicAdd(&ws[224 + i], sh_hi[0][2][i]);
        }
        if (sh_hi[1][0][i] != 0.0f) {
            atomicAdd(&ws[ACC_STRIDE + 4 + i],   sh_hi[1][0][i]);
            atomicAdd(&ws[ACC_STRIDE + 114 + i], sh_hi[1][1][i]);
            atomicAdd(&ws[ACC_STRIDE + 224 + i], sh_hi[1][2][i]);
        }
    }
}

__global__ void ohem_finalize(const float* __restrict__ ws, float* __restrict__ out)
{
    // single 64-thread block: reduce 64 striped sets, then OHEM logic on lane 0
    int lane = threadIdx.x;   // 0..63
    float v[8];
    #pragma unroll
    for (int k = 0; k < 8; ++k) v[k] = ws[SET_BASE + lane * 16 + k];
    #pragma unroll
    for (int off = 32; off > 0; off >>= 1) {
        #pragma unroll
        for (int k = 0; k < 8; ++k) v[k] += __shfl_down(v[k], off);
    }
    if (lane != 0) return;

    float nv = v[0];
    float loss[2];
    for (int pr = 0; pr < 2; ++pr) {
        const float* a = ws + pr * ACC_STRIDE;
        float sw   = pr ? v[4] : v[1];
        float swlp = pr ? v[5] : v[2];
        float cle  = pr ? v[6] : v[3];
        float l;
        if (nv <= (float)MIN_KEPT) {
            float tw = sw, twlp = swlp;
            for (int b = 0; b < NHI; ++b) { tw += a[114 + b]; twlp += a[224 + b]; }
            l = twlp / tw;
        } else if (cle >= (float)MIN_KEPT) {
            l = swlp / sw;
        } else {
            float cum = cle, tw = sw, twlp = swlp;
            for (int b = 0; b < NHI; ++b) {
                cum  += a[4 + b];
                tw   += a[114 + b];
                twlp += a[224 + b];
                if (cum >= (float)MIN_KEPT) break;
            }
            l = twlp / tw;
        }
        loss[pr] = l;
    }
    out[0] = 0.4f * loss[0] + loss[1];
}

extern "C" void kernel_launch(void* const* d_in, const int* in_sizes, int n_in,
                              void* d_out, int out_size, void* d_ws, size_t ws_size,
                              hipStream_t stream)
{
    const float* pred1  = (const float*)d_in[0];
    const float* pred2  = (const float*)d_in[1];
    const int*   target = (const int*)d_in[2];
    float* out = (float*)d_out;
    float* ws  = (float*)d_ws;

    // zero hist (ws[0..2047]) + striped sets (ws[2048..3071])
    hipMemsetAsync(d_ws, 0, 3072 * sizeof(float), stream);

    ohem_row<<<dim3(N_BATCH * H_OUT), 256, 0, stream>>>(pred1, pred2, target, ws);
    ohem_finalize<<<1, 64, 0, stream>>>(ws, out);
}